// Round 6
// baseline (12772.416 us; speedup 1.0000x reference)
//
#include <hip/hip_runtime.h>

typedef unsigned short u16;
typedef unsigned int   u32;
typedef unsigned char  u8;

constexpr int kB = 32, kT = 128, kS = 256, kE = 512, kH = 1024, kG = 4096;

typedef __attribute__((ext_vector_type(8))) short bfx8;
typedef __attribute__((ext_vector_type(4))) float fx4;

__device__ __forceinline__ float b2f(u16 v){ return __uint_as_float(((u32)v) << 16); }
__device__ __forceinline__ u16  f2b(float f){
    u32 u = __float_as_uint(f);
    return (u16)((u + 0x7FFFu + ((u >> 16) & 1u)) >> 16);
}
__device__ __forceinline__ float sigf(float x){ return 1.f / (1.f + expf(-x)); }
// dt==0: buffer is bf16 (u16); dt==1: buffer is fp32 (validated: fp32 on this harness)
__device__ __forceinline__ float ldin(const void* p, size_t i, int dt){
    return dt ? ((const float*)p)[i] : b2f(((const u16*)p)[i]);
}

// ---------------- input dtype detection (bf16 vs fp32) ----------------
__global__ void detect_dtype_k(const void* __restrict__ inputs, int* __restrict__ dtflag)
{
    __shared__ int bad;
    int t = threadIdx.x;
    if (t == 0) bad = 0;
    __syncthreads();
    const u16* p = (const u16*)inputs;
    int l = 0;
    for (int i = t; i < 4096; i += 256){
        u16 v = p[i];
        int e = (v >> 7) & 0xFF;
        if (v != 0 && (e < 90 || e > 140)) l = 1;
    }
    if (l) atomicOr(&bad, 1);
    __syncthreads();
    if (t == 0) *dtflag = bad;   // 1 = fp32, 0 = bf16
}

// ---------------- mask detection -> maskflag[b][s] = 1.0 (pad) / 0.0 ----------------
__global__ void prep_mask_k(const void* __restrict__ mask, float* __restrict__ maskflag)
{
    __shared__ int bad32, bad16, bad8, evenNZ;
    int t = threadIdx.x;
    if (t == 0){ bad32 = 0; bad16 = 0; bad8 = 0; evenNZ = 0; }
    __syncthreads();
    const u32* w32 = (const u32*)mask;
    const u16* w16 = (const u16*)mask;
    const u8*  w8  = (const u8*)mask;
    int l32 = 0, l16 = 0, l8 = 0, lev = 0;
    for (int i = t; i < 2048; i += 256){ u32 v = w32[i]; l32 |= (v > 1u); }
    for (int i = t; i < 4096; i += 256){
        u16 v = w16[i];
        l16 |= (v != 0 && v != 0x3F80u);
        if ((i & 1) == 0 && v != 0) lev = 1;
    }
    for (int i = t; i < 8192; i += 256){ l8 |= (w8[i] > 1); }
    if (l32) atomicOr(&bad32, 1);
    if (l16) atomicOr(&bad16, 1);
    if (l8)  atomicOr(&bad8, 1);
    if (lev) atomicOr(&evenNZ, 1);
    __syncthreads();
    int mode;                       // 0=int32, 1=bf16, 2=uint8, 3=fp32
    if (!bad32)       mode = 0;
    else if (!bad16)  mode = evenNZ ? 1 : 3;
    else if (!bad8)   mode = 2;
    else              mode = 3;
    for (int i = t; i < kB * kS; i += 256){
        bool m;
        if (mode == 0)      m = (((const int*)mask)[i] != 0);
        else if (mode == 1) m = (w16[i] != 0);
        else if (mode == 2) m = (w8[i] != 0);
        else                m = (((const float*)mask)[i] != 0.f);
        maskflag[i] = m ? 1.f : 0.f;
    }
}

// ---------------- bias / fold-vector precompute ----------------
__global__ void prep_bias_k(const void* __restrict__ Wq, const void* __restrict__ bq,
                            const void* __restrict__ Wk, const void* __restrict__ bk,
                            const void* __restrict__ bv, const void* __restrict__ Wo,
                            const void* __restrict__ bo,
                            const void* __restrict__ bih0, const void* __restrict__ bhh0,
                            const void* __restrict__ bih1, const void* __restrict__ bhh1,
                            float* __restrict__ bkq, float* __restrict__ bvo,
                            float* __restrict__ ubq, float* __restrict__ bof,
                            float* __restrict__ bias01, float* __restrict__ bias1,
                            float* __restrict__ cbqbk, const int* __restrict__ dtflag)
{
    int dt = *dtflag;
    int idx = blockIdx.x * 256 + threadIdx.x;
    if (idx < 1024){
        float s = 0.f;
        for (int i = 0; i < 1024; i++) s += ldin(bk, i, dt) * ldin(Wq, (size_t)i * 1024 + idx, dt);
        bkq[idx] = s;
    } else if (idx < 2048){ int o2 = idx - 1024;
        float s = 0.f;
        for (int h = 0; h < 1024; h++) s += ldin(bv, h, dt) * ldin(Wo, (size_t)o2 * 1024 + h, dt);
        bvo[o2] = s;
    } else if (idx < 3072){ int e = idx - 2048;
        float s = 0.f;
        for (int i = 0; i < 1024; i++) s += ldin(bq, i, dt) * ldin(Wk, (size_t)i * 1024 + e, dt);
        ubq[e] = s;
    } else if (idx < 4096){ int o2 = idx - 3072;
        bof[o2] = ldin(bo, o2, dt);
    } else if (idx < 8192){ int j = idx - 4096;
        bias01[j] = ldin(bih0, j, dt) + ldin(bhh0, j, dt);
    } else if (idx < 12288){ int j = idx - 8192;
        bias1[j] = ldin(bih1, j, dt) + ldin(bhh1, j, dt);
    } else if (idx == 12288){
        float s = 0.f;
        for (int i = 0; i < 1024; i++) s += ldin(bq, i, dt) * ldin(bk, i, dt);
        cbqbk[0] = s;
    }
}

// ---------------- initial states: c from enc_c; zero double-buffered h; zero counters ----------------
__global__ void init_state_k(const void* __restrict__ enc_c,
                             float* __restrict__ c0, float* __restrict__ c1,
                             u16* __restrict__ H0h, u16* __restrict__ H0l,
                             u16* __restrict__ H1h, u16* __restrict__ H1l,
                             int* __restrict__ cnt,
                             const int* __restrict__ dtflag)
{
    int dt = *dtflag;
    int idx = blockIdx.x * 256 + threadIdx.x;     // 32768
    int b = idx >> 10, h = idx & 1023;
    float cv = (h < 512) ? ldin(enc_c, (size_t)b * 512 + h, dt)
                         : ldin(enc_c, (size_t)(32 + b) * 512 + (h - 512), dt);
    c0[idx] = cv; c1[idx] = cv;
    H0h[idx] = 0; H0h[32768 + idx] = 0;
    H0l[idx] = 0; H0l[32768 + idx] = 0;
    H1h[idx] = 0; H1h[32768 + idx] = 0;
    H1l[idx] = 0; H1l[32768 + idx] = 0;
    if (idx < 128) cnt[idx] = 0;
}

// ---------------- elementwise hi/lo bf16 split (same layout) ----------------
__global__ void split_plain_k(const void* __restrict__ src, u16* __restrict__ Oh,
                              u16* __restrict__ Ol, int n, const int* __restrict__ dtflag)
{
    int dt = *dtflag;
    int idx = blockIdx.x * 256 + threadIdx.x;
    if (idx >= n) return;
    float v = ldin(src, idx, dt);
    u16 h = f2b(v);
    Oh[idx] = h;
    Ol[idx] = f2b(v - b2f(h));
}

// ---------------- x split with (b,t)->m remap: X[(t*32+b)*512 + e] ----------------
__global__ void split_x_k(const void* __restrict__ inputs, u16* __restrict__ Xh,
                          u16* __restrict__ Xl, const int* __restrict__ dtflag)
{
    int dt = *dtflag;
    int idx = blockIdx.x * 256 + threadIdx.x;        // 2097152 = 32*128*512
    int b = idx >> 16, t = (idx >> 9) & 127, e = idx & 511;
    float v = ldin(inputs, idx, dt);
    u16 h = f2b(v);
    size_t o = ((size_t)(t * 32 + b) << 9) + e;
    Xh[o] = h;
    Xl[o] = f2b(v - b2f(h));
}

// ---------------- transpose + hi/lo split: O[c][r] = split(in[r][col_off + c]) ----------------
__global__ void tsplit_k(const void* __restrict__ W, int ldw, int col_off,
                         u16* __restrict__ Oh, u16* __restrict__ Ol, int ldo,
                         const int* __restrict__ dtflag)
{
    __shared__ float tile[64][65];
    int dt = *dtflag;
    int r0 = blockIdx.x * 64, c0 = blockIdx.y * 64;
    for (int i = 0; i < 16; i++){
        int idx = threadIdx.x + i * 256;
        int rr = idx >> 6, cc = idx & 63;
        tile[rr][cc] = ldin(W, (size_t)(r0 + rr) * ldw + col_off + c0 + cc, dt);
    }
    __syncthreads();
    for (int i = 0; i < 16; i++){
        int idx = threadIdx.x + i * 256;
        int cr = idx >> 6, rc = idx & 63;
        float v = tile[rc][cr];
        u16 h = f2b(v);
        size_t o = (size_t)(c0 + cr) * ldo + r0 + rc;
        Oh[o] = h;
        Ol[o] = f2b(v - b2f(h));
    }
}

// ---------------- weight frag reorder: F[ct][ks][lane][j], KSS k-slices ----------------
__global__ __launch_bounds__(256) void wfrag_k(const void* __restrict__ W, int ldw, int col_off,
                                               u16* __restrict__ F, int KSS,
                                               const int* __restrict__ dtflag)
{
    int dt = *dtflag;
    int ct = blockIdx.x;                 // 0..255 (16 output cols each)
    int iters = KSS * 2;                 // KSS*512 / 256
    for (int i = 0; i < iters; i++){
        int flat = threadIdx.x + i * 256;
        int ks = flat >> 9, r = flat & 511, l = r >> 3, j = r & 7;
        int row = ct * 16 + (l & 15);
        int k = ks * 32 + (l >> 4) * 8 + j;
        F[(size_t)ct * (KSS * 512) + flat] = f2b(ldin(W, (size_t)row * ldw + col_off + k, dt));
    }
}

// ---------------- generic hi/lo MFMA GEMM: Out[m][n] = sum_k A[m][k]*B[k][n], K=1024 ----------------
// EPI 0: hi/lo fp32-split bf16 out. EPI 1: bf16 out remapped [b][s][n] (+bias,*scale); Out2 (optional) [b][n][s].
template<int EPI>
__global__ __launch_bounds__(256) void gemm_hilo_k(
    const u16* __restrict__ Ah, const u16* __restrict__ Al, int ldA,
    const u16* __restrict__ Bh, const u16* __restrict__ Bl, int ldB,
    u16* __restrict__ OutH, u16* __restrict__ OutL, int ldO,
    const float* __restrict__ bias, float scale, u16* __restrict__ Out2)
{
    __shared__ __align__(16) u16 Bsh[64][40];
    __shared__ __align__(16) u16 Bsl[64][40];
    int tid = threadIdx.x, wave = tid >> 6, lane = tid & 63;
    int m0 = blockIdx.x * 64, n0 = blockIdx.y * 64;
    int rA = lane & 15, kq = lane >> 4;
    fx4 acc[4];
    #pragma unroll
    for (int nt = 0; nt < 4; nt++) acc[nt] = (fx4){0.f, 0.f, 0.f, 0.f};
    int skk = tid >> 3, snn = (tid & 7) * 8;
    for (int k0 = 0; k0 < 1024; k0 += 32){
        bfx8 vh = *(const bfx8*)(Bh + (size_t)(k0 + skk) * ldB + n0 + snn);
        bfx8 vl = *(const bfx8*)(Bl + (size_t)(k0 + skk) * ldB + n0 + snn);
        __syncthreads();
        #pragma unroll
        for (int q = 0; q < 8; q++){ Bsh[snn + q][skk] = (u16)vh[q]; Bsl[snn + q][skk] = (u16)vl[q]; }
        __syncthreads();
        size_t abase = (size_t)(m0 + wave * 16 + rA) * ldA + k0 + kq * 8;
        bfx8 a_h = *(const bfx8*)(Ah + abase);
        bfx8 a_l = *(const bfx8*)(Al + abase);
        #pragma unroll
        for (int nt = 0; nt < 4; nt++){
            bfx8 b_h = *(const bfx8*)&Bsh[nt * 16 + rA][kq * 8];
            bfx8 b_l = *(const bfx8*)&Bsl[nt * 16 + rA][kq * 8];
            acc[nt] = __builtin_amdgcn_mfma_f32_16x16x32_bf16(a_h, b_h, acc[nt], 0, 0, 0);
            acc[nt] = __builtin_amdgcn_mfma_f32_16x16x32_bf16(a_h, b_l, acc[nt], 0, 0, 0);
            acc[nt] = __builtin_amdgcn_mfma_f32_16x16x32_bf16(a_l, b_h, acc[nt], 0, 0, 0);
        }
    }
    #pragma unroll
    for (int nt = 0; nt < 4; nt++){
        #pragma unroll
        for (int i = 0; i < 4; i++){
            int m = m0 + wave * 16 + kq * 4 + i;
            int n = n0 + nt * 16 + rA;
            float v = acc[nt][i];
            if (EPI == 0){
                u16 h = f2b(v);
                OutH[(size_t)m * ldO + n] = h;
                OutL[(size_t)m * ldO + n] = f2b(v - b2f(h));
            } else {
                float v2 = (v + bias[n]) * scale;
                u16 ov = f2b(v2);
                int b = m & 31, s = m >> 5;
                OutH[(((size_t)((b << 8) | s)) << 10) + n] = ov;
                if (Out2) Out2[((size_t)b * 1024 + n) * 256 + s] = ov;
            }
        }
    }
}

// ---------------- skbqs[b][s] = (bq.K[s,b,:]) * scale ----------------
__global__ __launch_bounds__(256) void skbq_k(
    const void* __restrict__ enc, const float* __restrict__ ubq,
    const float* __restrict__ cbqbk, float* __restrict__ skbqs,
    const int* __restrict__ dtflag)
{
    int dt = *dtflag;
    int w = (blockIdx.x * 256 + threadIdx.x) >> 6;   // 0..8191 = s*32+b
    int lane = threadIdx.x & 63;
    int s = w >> 5, b = w & 31;
    size_t base = (size_t)w * 1024 + lane * 16;
    float acc = 0.f;
    #pragma unroll
    for (int i = 0; i < 16; i++) acc += ubq[lane * 16 + i] * ldin(enc, base + i, dt);
    #pragma unroll
    for (int off = 32; off; off >>= 1) acc += __shfl_down(acc, off, 64);
    if (lane == 0) skbqs[b * 256 + s] = (acc + cbqbk[0]) * 0.03125f;
}

// ---------------- prologue: psc[0][b][s] = c1.KQb full dot; slices 1..63 = 0 ----------------
__global__ __launch_bounds__(256) void psc0_k(
    const float* __restrict__ c1f, const u16* __restrict__ KQb, float* __restrict__ psc)
{
    int gid = blockIdx.x * 256 + threadIdx.x;         // 0..524287
    if (gid >= 8192) psc[gid] = 0.f;                  // zero slices 1..63
    int w = gid >> 6;                                 // 0..8191
    int lane = threadIdx.x & 63;
    int b = w >> 8, s = w & 255;
    const u16*  kr = KQb + (((size_t)((b << 8) | s)) << 10) + lane * 16;
    const float* cr = c1f + ((size_t)b << 10) + lane * 16;
    float cb[16];
    *(float4*)&cb[0]  = *(const float4*)(cr);
    *(float4*)&cb[4]  = *(const float4*)(cr + 4);
    *(float4*)&cb[8]  = *(const float4*)(cr + 8);
    *(float4*)&cb[12] = *(const float4*)(cr + 12);
    u32 kb[8];
    *(uint4*)&kb[0] = *(const uint4*)(kr);
    *(uint4*)&kb[4] = *(const uint4*)(kr + 8);
    float acc = 0.f;
    #pragma unroll
    for (int i = 0; i < 8; i++){
        acc += cb[2 * i]     * b2f((u16)(kb[i] & 0xFFFFu));
        acc += cb[2 * i + 1] * b2f((u16)(kb[i] >> 16));
    }
    #pragma unroll
    for (int off = 32; off; off >>= 1) acc += __shfl_down(acc, off, 64);
    if (lane == 0) psc[b * 256 + s] = acc;            // slice 0
}

// ---------------- per-step: softmax over 64 psc slices + ctx = attn@Vob + bo -> Ch/Cl ----------------
// grid 256 = (b<<3 | ht), ht covers 128 h each
__global__ __launch_bounds__(256) void smctx_k(
    const float* __restrict__ psc, const float* __restrict__ skbqs,
    const float* __restrict__ maskflag, const u16* __restrict__ Vob,
    const float* __restrict__ bof, u16* __restrict__ Ch, u16* __restrict__ Cl)
{
    __shared__ float attn[256];
    __shared__ float wred[8];
    __shared__ float2 part[4][64];
    int b = blockIdx.x >> 3, ht = blockIdx.x & 7;
    int tid = threadIdx.x;
    int is = (b << 8) + tid;
    float scv;
    if (maskflag[is] != 0.f) scv = -1e9f;
    else {
        const float* pp = psc + is;
        float s0 = 0.f, s1 = 0.f, s2 = 0.f, s3 = 0.f;
        #pragma unroll
        for (int k = 0; k < 64; k += 4){
            s0 += pp[(size_t)k * 8192];
            s1 += pp[(size_t)(k + 1) * 8192];
            s2 += pp[(size_t)(k + 2) * 8192];
            s3 += pp[(size_t)(k + 3) * 8192];
        }
        scv = (s0 + s1) + (s2 + s3) + skbqs[is];
    }
    float m = scv;
    #pragma unroll
    for (int off = 32; off; off >>= 1) m = fmaxf(m, __shfl_down(m, off, 64));
    if ((tid & 63) == 0) wred[tid >> 6] = m;
    __syncthreads();
    float mm = fmaxf(fmaxf(wred[0], wred[1]), fmaxf(wred[2], wred[3]));
    float ex = expf(scv - mm);
    float ssum = ex;
    #pragma unroll
    for (int off = 32; off; off >>= 1) ssum += __shfl_down(ssum, off, 64);
    if ((tid & 63) == 0) wred[4 + (tid >> 6)] = ssum;
    __syncthreads();
    float tot = (wred[4] + wred[5]) + (wred[6] + wred[7]);
    attn[tid] = ex / tot;
    __syncthreads();
    int hl = tid & 63, scn = tid >> 6;
    int h2 = ht * 128 + hl * 2;
    const u16* vcol = Vob + ((size_t)b << 18) + h2;
    float a0 = 0.f, a1 = 0.f;
    #pragma unroll 8
    for (int s = scn; s < 256; s += 4){
        u32 v = *(const u32*)(vcol + ((size_t)s << 10));
        float at = attn[s];
        a0 += at * b2f((u16)(v & 0xFFFFu));
        a1 += at * b2f((u16)(v >> 16));
    }
    part[scn][hl] = make_float2(a0, a1);
    __syncthreads();
    if (tid < 64){
        float2 p0 = part[0][tid], p1 = part[1][tid], p2 = part[2][tid], p3 = part[3][tid];
        int h = ht * 128 + tid * 2;
        float v0 = p0.x + p1.x + p2.x + p3.x + bof[h];
        float v1 = p0.y + p1.y + p2.y + p3.y + bof[h + 1];
        u16 h0 = f2b(v0), h1 = f2b(v1);
        int base = (b << 10) + h;
        Ch[base] = h0;     Ch[base + 1] = h1;
        Cl[base] = f2b(v0 - b2f(h0));
        Cl[base + 1] = f2b(v1 - b2f(h1));
    }
}

// ---------------- gates MFMA + fan-in LSTM cell tail, grid (64 ht, 4 q) x 256 thr ----------------
// LAYER 0: slices ctx(0-31), h0(32-63), x(64-79); per wave 5. Tail: cell0 for 16-h slice.
// LAYER 1: slices h0new(0-31), h1(32-63); per wave 4. Tail: cell1 + y + psc[ht][b][s] from KQbT.
template<int LAYER>
__global__ __launch_bounds__(256) void gmm_k(
    const u16* __restrict__ f0, const u16* __restrict__ f1, const u16* __restrict__ f2,
    const u16* __restrict__ a0h, const u16* __restrict__ a0l,
    const u16* __restrict__ a1h, const u16* __restrict__ a1l,
    const u16* __restrict__ a2h, const u16* __restrict__ a2l,
    float* __restrict__ pp, int* __restrict__ cnt,
    const float* __restrict__ biasv, float* __restrict__ c_state,
    u16* __restrict__ outHh, u16* __restrict__ outHl,
    float* __restrict__ y_out, int t,
    const u16* __restrict__ KQbT, float* __restrict__ psc)
{
    __shared__ float red[4][32][64];
    int ht = blockIdx.x, q = blockIdx.y;
    int tid = threadIdx.x, wave = tid >> 6, lane = tid & 63;
    int rA = lane & 15, kq = lane >> 4;
    constexpr int PER_W = (LAYER == 0) ? 5 : 4;
    fx4 acc[2][4];
    #pragma unroll
    for (int mt = 0; mt < 2; mt++)
        #pragma unroll
        for (int nt = 0; nt < 4; nt++) acc[mt][nt] = (fx4){0.f, 0.f, 0.f, 0.f};

    #pragma unroll
    for (int si = 0; si < PER_W; si++){
        int s = q * (PER_W * 4) + wave * PER_W + si;
        const u16 *F, *ah, *al; int ks, ld, KSSF;
        if (LAYER == 0){
            if (s < 32)      { F = f0; ks = s;      ah = a0h; al = a0l; ld = 1024; KSSF = 32; }
            else if (s < 64) { F = f1; ks = s - 32; ah = a1h; al = a1l; ld = 1024; KSSF = 32; }
            else             { F = f2; ks = s - 64; ah = a2h; al = a2l; ld = 512;  KSSF = 16; }
        } else {
            if (s < 32)      { F = f0; ks = s;      ah = a0h; al = a0l; }
            else             { F = f1; ks = s - 32; ah = a1h; al = a1l; }
            ld = 1024; KSSF = 32;
        }
        int koff = ks * 32 + kq * 8;
        bfx8 a_h0 = *(const bfx8*)(ah + (size_t)rA * ld + koff);
        bfx8 a_l0 = *(const bfx8*)(al + (size_t)rA * ld + koff);
        bfx8 a_h1 = *(const bfx8*)(ah + (size_t)(16 + rA) * ld + koff);
        bfx8 a_l1 = *(const bfx8*)(al + (size_t)(16 + rA) * ld + koff);
        #pragma unroll
        for (int nt = 0; nt < 4; nt++){
            bfx8 bf = *(const bfx8*)(F + ((size_t)((nt * 64 + ht) * KSSF + ks) * 64 + lane) * 8);
            acc[0][nt] = __builtin_amdgcn_mfma_f32_16x16x32_bf16(a_h0, bf, acc[0][nt], 0, 0, 0);
            acc[0][nt] = __builtin_amdgcn_mfma_f32_16x16x32_bf16(a_l0, bf, acc[0][nt], 0, 0, 0);
            acc[1][nt] = __builtin_amdgcn_mfma_f32_16x16x32_bf16(a_h1, bf, acc[1][nt], 0, 0, 0);
            acc[1][nt] = __builtin_amdgcn_mfma_f32_16x16x32_bf16(a_l1, bf, acc[1][nt], 0, 0, 0);
        }
    }
    // C/D layout: col = lane&15 (rA), row = kq*4 + i; rows are b (mt*16 +)
    #pragma unroll
    for (int mt = 0; mt < 2; mt++)
        #pragma unroll
        for (int nt = 0; nt < 4; nt++)
            #pragma unroll
            for (int i = 0; i < 4; i++)
                red[wave][mt * 16 + kq * 4 + i][nt * 16 + rA] = acc[mt][nt][i];
    __syncthreads();
    #pragma unroll
    for (int i = 0; i < 8; i++){
        int flat = tid + i * 256;             // 0..2047
        int b = flat >> 6, cl = flat & 63;
        int nt = cl >> 4, hl = cl & 15;
        float v = (red[0][b][cl] + red[1][b][cl]) + (red[2][b][cl] + red[3][b][cl]);
        pp[(((size_t)(q * 32 + b)) << 12) + nt * 1024 + ht * 16 + hl] = v;
    }
    // ---- fan-in: last of the 4 q-blocks for this ht runs the cell ----
    __threadfence();
    __syncthreads();
    __shared__ int lastFlag;
    if (tid == 0) lastFlag = (atomicAdd(&cnt[ht], 1) == 3);
    __syncthreads();
    if (!lastFlag) return;
    __threadfence();   // acquire: other blocks' pp writes
    __shared__ float cs2[512];
    #pragma unroll
    for (int it = 0; it < 2; it++){
        int cell = tid + it * 256;            // 0..511 = (b, hl)
        int b = cell >> 4, hl = cell & 15;
        int hidx = ht * 16 + hl;
        float g[4];
        #pragma unroll
        for (int gate = 0; gate < 4; gate++){
            int j = gate * 1024 + hidx;
            g[gate] = biasv[j]
                    + pp[(((size_t)(0 * 32 + b)) << 12) + j]
                    + pp[(((size_t)(1 * 32 + b)) << 12) + j]
                    + pp[(((size_t)(2 * 32 + b)) << 12) + j]
                    + pp[(((size_t)(3 * 32 + b)) << 12) + j];
        }
        float gi_ = sigf(g[0]);
        float gf_ = sigf(g[1]);
        float gg_ = tanhf(g[2]);
        float go_ = sigf(g[3]);
        int cidx = (b << 10) + hidx;
        float c = gf_ * c_state[cidx] + gi_ * gg_;
        c_state[cidx] = c;
        float hv = go_ * tanhf(c);
        u16 hh = f2b(hv);
        outHh[cidx] = hh;
        outHl[cidx] = f2b(hv - b2f(hh));
        if (LAYER == 1){
            y_out[((size_t)b * kT + t) * kH + hidx] = hv;
            cs2[cell] = c;
        }
    }
    if (LAYER == 1){
        __syncthreads();
        // psc[ht][b][s] = sum_{hl} c1[b][ht*16+hl] * KQbT[b][ht*16+hl][s]; coalesced in s.
        int wv = tid >> 6, ln = tid & 63;
        #pragma unroll
        for (int bi = 0; bi < 8; bi++){
            int bb = wv * 8 + bi;
            float a0 = 0.f, a1 = 0.f, a2 = 0.f, a3 = 0.f;
            #pragma unroll
            for (int hl2 = 0; hl2 < 16; hl2++){
                float cv = cs2[(bb << 4) + hl2];
                const u16* kp = KQbT + ((size_t)bb * 1024 + ht * 16 + hl2) * 256 + ln * 4;
                u32 w0 = *(const u32*)kp;
                u32 w1 = *(const u32*)(kp + 2);
                a0 += cv * b2f((u16)(w0 & 0xFFFFu));
                a1 += cv * b2f((u16)(w0 >> 16));
                a2 += cv * b2f((u16)(w1 & 0xFFFFu));
                a3 += cv * b2f((u16)(w1 >> 16));
            }
            *(float4*)&psc[((size_t)ht * 32 + bb) * 256 + ln * 4] = make_float4(a0, a1, a2, a3);
        }
    }
    if (tid == 0) cnt[ht] = 0;    // reset for next launch
}

extern "C" void kernel_launch(void* const* d_in, const int* in_sizes, int n_in,
                              void* d_out, int out_size, void* d_ws, size_t ws_size,
                              hipStream_t stream)
{
    const void* inputs = d_in[0];
    const void* enc    = d_in[1];
    const void* enc_c  = d_in[2];
    const void* mask   = d_in[3];
    const void* Wq   = d_in[4];
    const void* bq   = d_in[5];
    const void* Wk   = d_in[6];
    const void* bk   = d_in[7];
    const void* Wv   = d_in[8];
    const void* bv   = d_in[9];
    const void* Wo   = d_in[10];
    const void* bo   = d_in[11];
    const void* Wih0 = d_in[12];
    const void* Whh0 = d_in[13];
    const void* bih0 = d_in[14];
    const void* bhh0 = d_in[15];
    const void* Wih1 = d_in[16];
    const void* Whh1 = d_in[17];
    const void* bih1 = d_in[18];
    const void* bhh1 = d_in[19];
    float* out = (float*)d_out;
    (void)in_sizes; (void)n_in; (void)out_size; (void)ws_size;

    char* ws = (char*)d_ws;
    size_t off = 0;
    auto alloc = [&](size_t bytes) -> void* {
        void* p = ws + off; off += (bytes + 255) & ~(size_t)255; return p;
    };
    // POOL_A (37.75MB): Eh/El (split enc, dead after enc GEMMs)  ||  F0c,F0h,F1i,F1h,F0x (wfrag, loop)
    char* poolA = (char*)alloc((size_t)37748736);
    u16* Eh  = (u16*)poolA;                              // 16.8MB
    u16* El  = (u16*)(poolA + 16777216);
    u16* F0c = (u16*)poolA;                              // 8.4MB each
    u16* F0h = (u16*)(poolA + 8388608);
    u16* F1i = (u16*)(poolA + 16777216);
    u16* F1h = (u16*)(poolA + 25165824);
    u16* F0x = (u16*)(poolA + 33554432);                 // 4.2MB
    // POOL_B (16.8MB): ww-GEMM operand splits (dead after ww GEMMs)
    char* poolB = (char*)alloc((size_t)16777216);
    u16* Akh  = (u16*)poolB;
    u16* Akl  = (u16*)(poolB + 2097152);
    u16* Bqh  = (u16*)(poolB + 4194304);
    u16* Bql  = (u16*)(poolB + 6291456);
    u16* Avh  = (u16*)(poolB + 8388608);
    u16* Avl  = (u16*)(poolB + 10485760);
    u16* Both = (u16*)(poolB + 12582912);
    u16* Botl = (u16*)(poolB + 14680064);
    u16*  KQb  = (u16*)alloc((size_t)kB * kS * kH * 2);    // [b][s][o] (scale 1/32 folded)
    u16*  KQbT = (u16*)alloc((size_t)kB * kH * kS * 2);    // [b][o][s] transposed copy
    u16*  Vob  = (u16*)alloc((size_t)kB * kS * kH * 2);    // [b][s][o2] (incl. bvo)
    u16*  Xh   = (u16*)alloc((size_t)kB * kT * kE * 2);    // [t*32+b][e]
    u16*  Xl   = (u16*)alloc((size_t)kB * kT * kE * 2);
    u16*  Wkqh = (u16*)alloc((size_t)kH * kH * 2);
    u16*  Wkql = (u16*)alloc((size_t)kH * kH * 2);
    u16*  Wvoh = (u16*)alloc((size_t)kH * kH * 2);
    u16*  Wvol = (u16*)alloc((size_t)kH * kH * 2);
    float* pp  = (float*)alloc((size_t)4 * kB * kG * 4);   // [4][32][4096] partials (shared L0/L1)
    float* psc = (float*)alloc((size_t)64 * kB * kS * 4);  // [64][b][s] score partials
    u16*  Ch   = (u16*)alloc((size_t)kB * kH * 2);
    u16*  Cl   = (u16*)alloc((size_t)kB * kH * 2);
    u16*  H0h  = (u16*)alloc((size_t)2 * kB * kH * 2);     // double-buffered
    u16*  H0l  = (u16*)alloc((size_t)2 * kB * kH * 2);
    u16*  H1h  = (u16*)alloc((size_t)2 * kB * kH * 2);
    u16*  H1l  = (u16*)alloc((size_t)2 * kB * kH * 2);
    float* c0f = (float*)alloc(kB * kH * 4);
    float* c1f = (float*)alloc(kB * kH * 4);
    float* bkq = (float*)alloc(1024 * 4);
    float* bvo = (float*)alloc(1024 * 4);
    float* ubq = (float*)alloc(1024 * 4);
    float* bof = (float*)alloc(1024 * 4);
    float* bias01 = (float*)alloc(4096 * 4);
    float* bias1  = (float*)alloc(4096 * 4);
    float* cbqbk  = (float*)alloc(256);
    float* skbqs  = (float*)alloc(kB * kS * 4);
    float* maskflag = (float*)alloc(kB * kS * 4);
    int*   cnt0 = (int*)alloc(64 * 4);
    int*   cnt1 = (int*)alloc(64 * 4);
    int*   dtflag = (int*)alloc(256);

    // ---- one-time precompute ----
    detect_dtype_k<<<1, 256, 0, stream>>>(inputs, dtflag);
    prep_mask_k<<<1, 256, 0, stream>>>(mask, maskflag);
    prep_bias_k<<<49, 256, 0, stream>>>(Wq, bq, Wk, bk, bv, Wo, bo,
                                        bih0, bhh0, bih1, bhh1,
                                        bkq, bvo, ubq, bof, bias01, bias1, cbqbk, dtflag);
    init_state_k<<<128, 256, 0, stream>>>(enc_c, c0f, c1f, H0h, H0l, H1h, H1l, cnt0, dtflag);
    split_plain_k<<<32768, 256, 0, stream>>>(enc, Eh, El, 8388608, dtflag);
    split_plain_k<<<4096, 256, 0, stream>>>(Wq, Bqh, Bql, 1048576, dtflag);
    tsplit_k<<<dim3(16, 16), 256, 0, stream>>>(Wk, 1024, 0, Akh, Akl, 1024, dtflag);
    tsplit_k<<<dim3(16, 16), 256, 0, stream>>>(Wv, 1024, 0, Avh, Avl, 1024, dtflag);
    tsplit_k<<<dim3(16, 16), 256, 0, stream>>>(Wo, 1024, 0, Both, Botl, 1024, dtflag);
    split_x_k<<<8192, 256, 0, stream>>>(inputs, Xh, Xl, dtflag);
    gemm_hilo_k<0><<<dim3(16, 16), 256, 0, stream>>>(Akh, Akl, 1024, Bqh, Bql, 1024,
                                                     Wkqh, Wkql, 1024, nullptr, 1.f, nullptr);
    gemm_hilo_k<0><<<dim3(16, 16), 256, 0, stream>>>(Avh, Avl, 1024, Both, Botl, 1024,
                                                     Wvoh, Wvol, 1024, nullptr, 1.f, nullptr);
    gemm_hilo_k<1><<<dim3(128, 16), 256, 0, stream>>>(Eh, El, 1024, Wkqh, Wkql, 1024,
                                                      KQb, nullptr, 0, bkq, 0.03125f, KQbT);
    gemm_hilo_k<1><<<dim3(128, 16), 256, 0, stream>>>(Eh, El, 1024, Wvoh, Wvol, 1024,
                                                      Vob, nullptr, 0, bvo, 1.0f, nullptr);
    skbq_k<<<2048, 256, 0, stream>>>(enc, ubq, cbqbk, skbqs, dtflag);
    wfrag_k<<<256, 256, 0, stream>>>(Wih0, 1536, 0,    F0c, 32, dtflag);
    wfrag_k<<<256, 256, 0, stream>>>(Whh0, 1024, 0,    F0h, 32, dtflag);
    wfrag_k<<<256, 256, 0, stream>>>(Wih0, 1536, 1024, F0x, 16, dtflag);
    wfrag_k<<<256, 256, 0, stream>>>(Wih1, 1024, 0,    F1i, 32, dtflag);
    wfrag_k<<<256, 256, 0, stream>>>(Whh1, 1024, 0,    F1h, 32, dtflag);
    psc0_k<<<2048, 256, 0, stream>>>(c1f, KQb, psc);

    // ---- recurrent loop: 3 kernels/step ----
    for (int t = 0; t < kT; t++){
        int rd = (t & 1) * kB * kH;        // prev-state slot (u16 elems)
        int wr = ((t + 1) & 1) * kB * kH;  // new-state slot
        smctx_k<<<256, 256, 0, stream>>>(psc, skbqs, maskflag, Vob, bof, Ch, Cl);
        gmm_k<0><<<dim3(64, 4), 256, 0, stream>>>(
            F0c, F0h, F0x, Ch, Cl, H0h + rd, H0l + rd,
            Xh + (size_t)t * 32 * kE, Xl + (size_t)t * 32 * kE,
            pp, cnt0, bias01, c0f, H0h + wr, H0l + wr,
            nullptr, t, nullptr, nullptr);
        gmm_k<1><<<dim3(64, 4), 256, 0, stream>>>(
            F1i, F1h, nullptr, H0h + wr, H0l + wr, H1h + rd, H1l + rd,
            nullptr, nullptr,
            pp, cnt1, bias1, c1f, H1h + wr, H1l + wr,
            out, t, KQbT, psc);
    }
}

// Round 7
// 5850.533 us; speedup vs baseline: 2.1831x; 2.1831x over previous
//
#include <hip/hip_runtime.h>

typedef unsigned short u16;
typedef unsigned int   u32;
typedef unsigned char  u8;

constexpr int kB = 32, kT = 128, kS = 256, kE = 512, kH = 1024, kG = 4096;

typedef __attribute__((ext_vector_type(8))) short bfx8;
typedef __attribute__((ext_vector_type(4))) float fx4;

__device__ __forceinline__ float b2f(u16 v){ return __uint_as_float(((u32)v) << 16); }
__device__ __forceinline__ u16  f2b(float f){
    u32 u = __float_as_uint(f);
    return (u16)((u + 0x7FFFu + ((u >> 16) & 1u)) >> 16);
}
__device__ __forceinline__ float sigf(float x){ return 1.f / (1.f + expf(-x)); }
// dt==0: buffer is bf16 (u16); dt==1: buffer is fp32 (validated: fp32 on this harness)
__device__ __forceinline__ float ldin(const void* p, size_t i, int dt){
    return dt ? ((const float*)p)[i] : b2f(((const u16*)p)[i]);
}

// ---------------- input dtype detection (bf16 vs fp32) ----------------
__global__ void detect_dtype_k(const void* __restrict__ inputs, int* __restrict__ dtflag)
{
    __shared__ int bad;
    int t = threadIdx.x;
    if (t == 0) bad = 0;
    __syncthreads();
    const u16* p = (const u16*)inputs;
    int l = 0;
    for (int i = t; i < 4096; i += 256){
        u16 v = p[i];
        int e = (v >> 7) & 0xFF;
        if (v != 0 && (e < 90 || e > 140)) l = 1;
    }
    if (l) atomicOr(&bad, 1);
    __syncthreads();
    if (t == 0) *dtflag = bad;   // 1 = fp32, 0 = bf16
}

// ---------------- mask detection -> maskflag[b][s] = 1.0 (pad) / 0.0 ----------------
__global__ void prep_mask_k(const void* __restrict__ mask, float* __restrict__ maskflag)
{
    __shared__ int bad32, bad16, bad8, evenNZ;
    int t = threadIdx.x;
    if (t == 0){ bad32 = 0; bad16 = 0; bad8 = 0; evenNZ = 0; }
    __syncthreads();
    const u32* w32 = (const u32*)mask;
    const u16* w16 = (const u16*)mask;
    const u8*  w8  = (const u8*)mask;
    int l32 = 0, l16 = 0, l8 = 0, lev = 0;
    for (int i = t; i < 2048; i += 256){ u32 v = w32[i]; l32 |= (v > 1u); }
    for (int i = t; i < 4096; i += 256){
        u16 v = w16[i];
        l16 |= (v != 0 && v != 0x3F80u);
        if ((i & 1) == 0 && v != 0) lev = 1;
    }
    for (int i = t; i < 8192; i += 256){ l8 |= (w8[i] > 1); }
    if (l32) atomicOr(&bad32, 1);
    if (l16) atomicOr(&bad16, 1);
    if (l8)  atomicOr(&bad8, 1);
    if (lev) atomicOr(&evenNZ, 1);
    __syncthreads();
    int mode;                       // 0=int32, 1=bf16, 2=uint8, 3=fp32
    if (!bad32)       mode = 0;
    else if (!bad16)  mode = evenNZ ? 1 : 3;
    else if (!bad8)   mode = 2;
    else              mode = 3;
    for (int i = t; i < kB * kS; i += 256){
        bool m;
        if (mode == 0)      m = (((const int*)mask)[i] != 0);
        else if (mode == 1) m = (w16[i] != 0);
        else if (mode == 2) m = (w8[i] != 0);
        else                m = (((const float*)mask)[i] != 0.f);
        maskflag[i] = m ? 1.f : 0.f;
    }
}

// ---------------- bias / fold-vector precompute ----------------
__global__ void prep_bias_k(const void* __restrict__ Wq, const void* __restrict__ bq,
                            const void* __restrict__ Wk, const void* __restrict__ bk,
                            const void* __restrict__ bv, const void* __restrict__ Wo,
                            const void* __restrict__ bo,
                            const void* __restrict__ bih0, const void* __restrict__ bhh0,
                            const void* __restrict__ bih1, const void* __restrict__ bhh1,
                            float* __restrict__ bkq, float* __restrict__ bvo,
                            float* __restrict__ ubq, float* __restrict__ bof,
                            float* __restrict__ bias01, float* __restrict__ bias1,
                            float* __restrict__ cbqbk, const int* __restrict__ dtflag)
{
    int dt = *dtflag;
    int idx = blockIdx.x * 256 + threadIdx.x;
    if (idx < 1024){
        float s = 0.f;
        for (int i = 0; i < 1024; i++) s += ldin(bk, i, dt) * ldin(Wq, (size_t)i * 1024 + idx, dt);
        bkq[idx] = s;
    } else if (idx < 2048){ int o2 = idx - 1024;
        float s = 0.f;
        for (int h = 0; h < 1024; h++) s += ldin(bv, h, dt) * ldin(Wo, (size_t)o2 * 1024 + h, dt);
        bvo[o2] = s;
    } else if (idx < 3072){ int e = idx - 2048;
        float s = 0.f;
        for (int i = 0; i < 1024; i++) s += ldin(bq, i, dt) * ldin(Wk, (size_t)i * 1024 + e, dt);
        ubq[e] = s;
    } else if (idx < 4096){ int o2 = idx - 3072;
        bof[o2] = ldin(bo, o2, dt);
    } else if (idx < 8192){ int j = idx - 4096;
        bias01[j] = ldin(bih0, j, dt) + ldin(bhh0, j, dt);
    } else if (idx < 12288){ int j = idx - 8192;
        bias1[j] = ldin(bih1, j, dt) + ldin(bhh1, j, dt);
    } else if (idx == 12288){
        float s = 0.f;
        for (int i = 0; i < 1024; i++) s += ldin(bq, i, dt) * ldin(bk, i, dt);
        cbqbk[0] = s;
    }
}

// ---------------- initial states: c0,c1 from enc_c; zero h hi/lo buffers ----------------
__global__ void init_state_k(const void* __restrict__ enc_c,
                             float* __restrict__ c0, float* __restrict__ c1,
                             u16* __restrict__ H0h, u16* __restrict__ H0l,
                             u16* __restrict__ H1h, u16* __restrict__ H1l,
                             const int* __restrict__ dtflag)
{
    int dt = *dtflag;
    int idx = blockIdx.x * 256 + threadIdx.x;     // 32768
    int b = idx >> 10, h = idx & 1023;
    float cv = (h < 512) ? ldin(enc_c, (size_t)b * 512 + h, dt)
                         : ldin(enc_c, (size_t)(32 + b) * 512 + (h - 512), dt);
    c0[idx] = cv; c1[idx] = cv;
    H0h[idx] = 0; H0l[idx] = 0;
    H1h[idx] = 0; H1l[idx] = 0;
}

// ---------------- elementwise hi/lo bf16 split (same layout) ----------------
__global__ void split_plain_k(const void* __restrict__ src, u16* __restrict__ Oh,
                              u16* __restrict__ Ol, int n, const int* __restrict__ dtflag)
{
    int dt = *dtflag;
    int idx = blockIdx.x * 256 + threadIdx.x;
    if (idx >= n) return;
    float v = ldin(src, idx, dt);
    u16 h = f2b(v);
    Oh[idx] = h;
    Ol[idx] = f2b(v - b2f(h));
}

// ---------------- x split with (b,t)->m remap: X[(t*32+b)*512 + e] ----------------
__global__ void split_x_k(const void* __restrict__ inputs, u16* __restrict__ Xh,
                          u16* __restrict__ Xl, const int* __restrict__ dtflag)
{
    int dt = *dtflag;
    int idx = blockIdx.x * 256 + threadIdx.x;        // 2097152 = 32*128*512
    int b = idx >> 16, t = (idx >> 9) & 127, e = idx & 511;
    float v = ldin(inputs, idx, dt);
    u16 h = f2b(v);
    size_t o = ((size_t)(t * 32 + b) << 9) + e;
    Xh[o] = h;
    Xl[o] = f2b(v - b2f(h));
}

// ---------------- transpose + hi/lo split: O[c][r] = split(in[r][col_off + c]) ----------------
__global__ void tsplit_k(const void* __restrict__ W, int ldw, int col_off,
                         u16* __restrict__ Oh, u16* __restrict__ Ol, int ldo,
                         const int* __restrict__ dtflag)
{
    __shared__ float tile[64][65];
    int dt = *dtflag;
    int r0 = blockIdx.x * 64, c0 = blockIdx.y * 64;
    for (int i = 0; i < 16; i++){
        int idx = threadIdx.x + i * 256;
        int rr = idx >> 6, cc = idx & 63;
        tile[rr][cc] = ldin(W, (size_t)(r0 + rr) * ldw + col_off + c0 + cc, dt);
    }
    __syncthreads();
    for (int i = 0; i < 16; i++){
        int idx = threadIdx.x + i * 256;
        int cr = idx >> 6, rc = idx & 63;
        float v = tile[rc][cr];
        u16 h = f2b(v);
        size_t o = (size_t)(c0 + cr) * ldo + r0 + rc;
        Oh[o] = h;
        Ol[o] = f2b(v - b2f(h));
    }
}

// ---------------- weight frag reorder: F[ct][ks][lane][j], KSS k-slices ----------------
__global__ __launch_bounds__(256) void wfrag_k(const void* __restrict__ W, int ldw, int col_off,
                                               u16* __restrict__ F, int KSS,
                                               const int* __restrict__ dtflag)
{
    int dt = *dtflag;
    int ct = blockIdx.x;                 // 0..255 (16 output cols each)
    int iters = KSS * 2;                 // KSS*512 / 256
    for (int i = 0; i < iters; i++){
        int flat = threadIdx.x + i * 256;
        int ks = flat >> 9, r = flat & 511, l = r >> 3, j = r & 7;
        int row = ct * 16 + (l & 15);
        int k = ks * 32 + (l >> 4) * 8 + j;
        F[(size_t)ct * (KSS * 512) + flat] = f2b(ldin(W, (size_t)row * ldw + col_off + k, dt));
    }
}

// ---------------- generic hi/lo MFMA GEMM: Out[m][n] = sum_k A[m][k]*B[k][n], K=1024 ----------------
template<int EPI>
__global__ __launch_bounds__(256) void gemm_hilo_k(
    const u16* __restrict__ Ah, const u16* __restrict__ Al, int ldA,
    const u16* __restrict__ Bh, const u16* __restrict__ Bl, int ldB,
    u16* __restrict__ OutH, u16* __restrict__ OutL, int ldO,
    const float* __restrict__ bias, float scale)
{
    __shared__ __align__(16) u16 Bsh[64][40];
    __shared__ __align__(16) u16 Bsl[64][40];
    int tid = threadIdx.x, wave = tid >> 6, lane = tid & 63;
    int m0 = blockIdx.x * 64, n0 = blockIdx.y * 64;
    int rA = lane & 15, kq = lane >> 4;
    fx4 acc[4];
    #pragma unroll
    for (int nt = 0; nt < 4; nt++) acc[nt] = (fx4){0.f, 0.f, 0.f, 0.f};
    int skk = tid >> 3, snn = (tid & 7) * 8;
    for (int k0 = 0; k0 < 1024; k0 += 32){
        bfx8 vh = *(const bfx8*)(Bh + (size_t)(k0 + skk) * ldB + n0 + snn);
        bfx8 vl = *(const bfx8*)(Bl + (size_t)(k0 + skk) * ldB + n0 + snn);
        __syncthreads();
        #pragma unroll
        for (int q = 0; q < 8; q++){ Bsh[snn + q][skk] = (u16)vh[q]; Bsl[snn + q][skk] = (u16)vl[q]; }
        __syncthreads();
        size_t abase = (size_t)(m0 + wave * 16 + rA) * ldA + k0 + kq * 8;
        bfx8 a_h = *(const bfx8*)(Ah + abase);
        bfx8 a_l = *(const bfx8*)(Al + abase);
        #pragma unroll
        for (int nt = 0; nt < 4; nt++){
            bfx8 b_h = *(const bfx8*)&Bsh[nt * 16 + rA][kq * 8];
            bfx8 b_l = *(const bfx8*)&Bsl[nt * 16 + rA][kq * 8];
            acc[nt] = __builtin_amdgcn_mfma_f32_16x16x32_bf16(a_h, b_h, acc[nt], 0, 0, 0);
            acc[nt] = __builtin_amdgcn_mfma_f32_16x16x32_bf16(a_h, b_l, acc[nt], 0, 0, 0);
            acc[nt] = __builtin_amdgcn_mfma_f32_16x16x32_bf16(a_l, b_h, acc[nt], 0, 0, 0);
        }
    }
    #pragma unroll
    for (int nt = 0; nt < 4; nt++){
        #pragma unroll
        for (int i = 0; i < 4; i++){
            int m = m0 + wave * 16 + kq * 4 + i;
            int n = n0 + nt * 16 + rA;
            float v = acc[nt][i];
            if (EPI == 0){
                u16 h = f2b(v);
                OutH[(size_t)m * ldO + n] = h;
                OutL[(size_t)m * ldO + n] = f2b(v - b2f(h));
            } else {
                float v2 = (v + bias[n]) * scale;
                OutH[(((size_t)(((m & 31) << 8) | (m >> 5))) << 10) + n] = f2b(v2);
            }
        }
    }
}

// ---------------- KQb [b][s][n] -> KQbT [b][n][s] tiled transpose ----------------
__global__ __launch_bounds__(256) void kqbT_k(const u16* __restrict__ KQb, u16* __restrict__ KQbT)
{
    __shared__ u16 tile[64][66];
    int bx = blockIdx.x;                  // 2048 = 32 b * 16 nb * 4 sb
    int b = bx >> 6, nb = (bx >> 2) & 15, sb = bx & 3;
    for (int i = 0; i < 16; i++){
        int idx = threadIdx.x + i * 256;  // 0..4095
        int sr = idx >> 6, nc = idx & 63;
        tile[sr][nc] = KQb[(((size_t)((b << 8) | (sb * 64 + sr))) << 10) + nb * 64 + nc];
    }
    __syncthreads();
    for (int i = 0; i < 16; i++){
        int idx = threadIdx.x + i * 256;
        int nr = idx >> 6, sc = idx & 63;
        KQbT[((size_t)b * 1024 + nb * 64 + nr) * 256 + sb * 64 + sc] = tile[sc][nr];
    }
}

// ---------------- skbqs[b][s] = (bq.K[s,b,:]) * scale ----------------
__global__ __launch_bounds__(256) void skbq_k(
    const void* __restrict__ enc, const float* __restrict__ ubq,
    const float* __restrict__ cbqbk, float* __restrict__ skbqs,
    const int* __restrict__ dtflag)
{
    int dt = *dtflag;
    int w = (blockIdx.x * 256 + threadIdx.x) >> 6;   // 0..8191 = s*32+b
    int lane = threadIdx.x & 63;
    int s = w >> 5, b = w & 31;
    size_t base = (size_t)w * 1024 + lane * 16;
    float acc = 0.f;
    #pragma unroll
    for (int i = 0; i < 16; i++) acc += ubq[lane * 16 + i] * ldin(enc, base + i, dt);
    #pragma unroll
    for (int off = 32; off; off >>= 1) acc += __shfl_down(acc, off, 64);
    if (lane == 0) skbqs[b * 256 + s] = (acc + cbqbk[0]) * 0.03125f;
}

// ---------------- gates MFMA partial: grid (64 ht, 4 q), 256 thr (4 waves) ----------------
// LAYER 0: slices ctx(0-31), h0(32-63), x(64-79); per wave 5.
// LAYER 1: slices h0new(0-31), h1(32-63); per wave 4.
// pp[q][b][gate*1024 + ht*16 + hl] partial over this block's K-range.
template<int LAYER>
__global__ __launch_bounds__(256) void gmm_k(
    const u16* __restrict__ f0, const u16* __restrict__ f1, const u16* __restrict__ f2,
    const u16* __restrict__ a0h, const u16* __restrict__ a0l,
    const u16* __restrict__ a1h, const u16* __restrict__ a1l,
    const u16* __restrict__ a2h, const u16* __restrict__ a2l,
    float* __restrict__ pp)
{
    __shared__ float red[4][32][64];
    int ht = blockIdx.x, q = blockIdx.y;
    int tid = threadIdx.x, wave = tid >> 6, lane = tid & 63;
    int rA = lane & 15, kq = lane >> 4;
    constexpr int PER_W = (LAYER == 0) ? 5 : 4;
    fx4 acc[2][4];
    #pragma unroll
    for (int mt = 0; mt < 2; mt++)
        #pragma unroll
        for (int nt = 0; nt < 4; nt++) acc[mt][nt] = (fx4){0.f, 0.f, 0.f, 0.f};

    #pragma unroll
    for (int si = 0; si < PER_W; si++){
        int s = q * (PER_W * 4) + wave * PER_W + si;
        const u16 *F, *ah, *al; int ks, ld, KSSF;
        if (LAYER == 0){
            if (s < 32)      { F = f0; ks = s;      ah = a0h; al = a0l; ld = 1024; KSSF = 32; }
            else if (s < 64) { F = f1; ks = s - 32; ah = a1h; al = a1l; ld = 1024; KSSF = 32; }
            else             { F = f2; ks = s - 64; ah = a2h; al = a2l; ld = 512;  KSSF = 16; }
        } else {
            if (s < 32)      { F = f0; ks = s;      ah = a0h; al = a0l; }
            else             { F = f1; ks = s - 32; ah = a1h; al = a1l; }
            ld = 1024; KSSF = 32;
        }
        int koff = ks * 32 + kq * 8;
        bfx8 a_h0 = *(const bfx8*)(ah + (size_t)rA * ld + koff);
        bfx8 a_l0 = *(const bfx8*)(al + (size_t)rA * ld + koff);
        bfx8 a_h1 = *(const bfx8*)(ah + (size_t)(16 + rA) * ld + koff);
        bfx8 a_l1 = *(const bfx8*)(al + (size_t)(16 + rA) * ld + koff);
        #pragma unroll
        for (int nt = 0; nt < 4; nt++){
            bfx8 bf = *(const bfx8*)(F + ((size_t)((nt * 64 + ht) * KSSF + ks) * 64 + lane) * 8);
            acc[0][nt] = __builtin_amdgcn_mfma_f32_16x16x32_bf16(a_h0, bf, acc[0][nt], 0, 0, 0);
            acc[0][nt] = __builtin_amdgcn_mfma_f32_16x16x32_bf16(a_l0, bf, acc[0][nt], 0, 0, 0);
            acc[1][nt] = __builtin_amdgcn_mfma_f32_16x16x32_bf16(a_h1, bf, acc[1][nt], 0, 0, 0);
            acc[1][nt] = __builtin_amdgcn_mfma_f32_16x16x32_bf16(a_l1, bf, acc[1][nt], 0, 0, 0);
        }
    }
    // C/D layout: col = lane&15 (rA), row = kq*4 + i; rows are b (mt*16 +)
    #pragma unroll
    for (int mt = 0; mt < 2; mt++)
        #pragma unroll
        for (int nt = 0; nt < 4; nt++)
            #pragma unroll
            for (int i = 0; i < 4; i++)
                red[wave][mt * 16 + kq * 4 + i][nt * 16 + rA] = acc[mt][nt][i];
    __syncthreads();
    #pragma unroll
    for (int i = 0; i < 8; i++){
        int flat = tid + i * 256;             // 0..2047
        int b = flat >> 6, cl = flat & 63;
        int nt = cl >> 4, hl = cl & 15;
        float v = (red[0][b][cl] + red[1][b][cl]) + (red[2][b][cl] + red[3][b][cl]);
        pp[(((size_t)(q * 32 + b)) << 12) + nt * 1024 + ht * 16 + hl] = v;
    }
}

// ---------------- layer-0 cell: g = sum_q pp + bias; update c0, h0 hi/lo ----------------
__global__ __launch_bounds__(256) void cell0_k(
    const float* __restrict__ pp, const float* __restrict__ biasv,
    float* __restrict__ c_state, u16* __restrict__ outHh, u16* __restrict__ outHl)
{
    int idx = blockIdx.x * 256 + threadIdx.x;     // 32768
    int b = idx >> 10, h = idx & 1023;
    float g[4];
    #pragma unroll
    for (int gate = 0; gate < 4; gate++){
        int j = gate * 1024 + h;
        g[gate] = biasv[j]
                + pp[(((size_t)(0 * 32 + b)) << 12) + j]
                + pp[(((size_t)(1 * 32 + b)) << 12) + j]
                + pp[(((size_t)(2 * 32 + b)) << 12) + j]
                + pp[(((size_t)(3 * 32 + b)) << 12) + j];
    }
    float gi_ = sigf(g[0]);
    float gf_ = sigf(g[1]);
    float gg_ = tanhf(g[2]);
    float go_ = sigf(g[3]);
    float c = gf_ * c_state[idx] + gi_ * gg_;
    c_state[idx] = c;
    float hv = go_ * tanhf(c);
    u16 hh = f2b(hv);
    outHh[idx] = hh;
    outHl[idx] = f2b(hv - b2f(hh));
}

// ---------------- fused: cell1(t-1) + scores + softmax + ctx(t) ----------------
// 32 blocks (b) x 1024 threads. t in [0,128]: cell part if t>0, attn part if t<128.
// scores read KQbT [b][n][s]: coalesced in s.
__global__ __launch_bounds__(1024) void fused_attn_k(
    const float* __restrict__ pp, const float* __restrict__ bias1,
    float* __restrict__ c1f, u16* __restrict__ H1h, u16* __restrict__ H1l,
    float* __restrict__ y_out, int t,
    const u16* __restrict__ KQbT, const u16* __restrict__ Vob,
    const float* __restrict__ skbqs, const float* __restrict__ maskflag,
    const float* __restrict__ bof, u16* __restrict__ Ch, u16* __restrict__ Cl)
{
    __shared__ float cs[1024];
    __shared__ float sred[16][260];
    __shared__ float attn[256];
    __shared__ float wred[8];
    __shared__ float2 cpart[2][512];
    int b = blockIdx.x, tid = threadIdx.x;
    float c;
    int cidx = (b << 10) + tid;
    if (t > 0){
        float g[4];
        #pragma unroll
        for (int gate = 0; gate < 4; gate++){
            int j = gate * 1024 + tid;
            g[gate] = bias1[j]
                    + pp[(((size_t)(0 * 32 + b)) << 12) + j]
                    + pp[(((size_t)(1 * 32 + b)) << 12) + j]
                    + pp[(((size_t)(2 * 32 + b)) << 12) + j]
                    + pp[(((size_t)(3 * 32 + b)) << 12) + j];
        }
        float gi_ = sigf(g[0]);
        float gf_ = sigf(g[1]);
        float gg_ = tanhf(g[2]);
        float go_ = sigf(g[3]);
        c = gf_ * c1f[cidx] + gi_ * gg_;
        c1f[cidx] = c;
        float hv = go_ * tanhf(c);
        u16 hh = f2b(hv);
        H1h[cidx] = hh;
        H1l[cidx] = f2b(hv - b2f(hh));
        y_out[(((size_t)b * kT + (t - 1)) << 10) + tid] = hv;
    } else {
        c = c1f[cidx];
    }
    cs[tid] = c;
    __syncthreads();
    if (t == 128) return;
    // ---- scores: thread (sp = tid&63 -> 4 s, hq = tid>>6 -> 64-h slice), coalesced in s ----
    {
        int sp = tid & 63, hq = tid >> 6;
        const u16* kp = KQbT + ((size_t)b * 1024 + hq * 64) * 256 + sp * 4;
        const float* cc = &cs[hq * 64];
        float a0 = 0.f, a1 = 0.f, a2 = 0.f, a3 = 0.f;
        #pragma unroll 8
        for (int i = 0; i < 64; i++){
            uint2 kv = *(const uint2*)(kp + (size_t)i * 256);
            float cv = cc[i];
            a0 += cv * b2f((u16)(kv.x & 0xFFFFu));
            a1 += cv * b2f((u16)(kv.x >> 16));
            a2 += cv * b2f((u16)(kv.y & 0xFFFFu));
            a3 += cv * b2f((u16)(kv.y >> 16));
        }
        sred[hq][sp * 4]     = a0;
        sred[hq][sp * 4 + 1] = a1;
        sred[hq][sp * 4 + 2] = a2;
        sred[hq][sp * 4 + 3] = a3;
    }
    __syncthreads();
    if (tid < 256){
        float sc = 0.f;
        #pragma unroll
        for (int hq = 0; hq < 16; hq++) sc += sred[hq][tid];
        int is = (b << 8) + tid;
        sc = (maskflag[is] != 0.f) ? -1e9f : sc + skbqs[is];
        attn[tid] = sc;
        float m = sc;
        #pragma unroll
        for (int off = 32; off; off >>= 1) m = fmaxf(m, __shfl_down(m, off, 64));
        if ((tid & 63) == 0) wred[tid >> 6] = m;
    }
    __syncthreads();
    if (tid < 256){
        float mm = fmaxf(fmaxf(wred[0], wred[1]), fmaxf(wred[2], wred[3]));
        float ex = expf(attn[tid] - mm);
        float ssum = ex;
        #pragma unroll
        for (int off = 32; off; off >>= 1) ssum += __shfl_down(ssum, off, 64);
        if ((tid & 63) == 0) wred[4 + (tid >> 6)] = ssum;
        sred[0][tid] = ex;
    }
    __syncthreads();
    if (tid < 256){
        float tot = (wred[4] + wred[5]) + (wred[6] + wred[7]);
        attn[tid] = sred[0][tid] / tot;
    }
    __syncthreads();
    // ---- ctx: thread (sh = tid>>9, hp = tid&511): 2 h, 128 s ----
    {
        int sh = tid >> 9, hp = tid & 511;
        const u16* vcol = Vob + ((size_t)b << 18) + hp * 2;
        float a0 = 0.f, a1 = 0.f;
        int s0 = sh * 128;
        #pragma unroll 8
        for (int s = s0; s < s0 + 128; s++){
            u32 v = *(const u32*)(vcol + ((size_t)s << 10));
            float at = attn[s];
            a0 += at * b2f((u16)(v & 0xFFFFu));
            a1 += at * b2f((u16)(v >> 16));
        }
        cpart[sh][hp] = make_float2(a0, a1);
    }
    __syncthreads();
    if (tid < 512){
        float2 p0 = cpart[0][tid], p1 = cpart[1][tid];
        int h = tid * 2;
        float v0 = p0.x + p1.x + bof[h];
        float v1 = p0.y + p1.y + bof[h + 1];
        u16 h0 = f2b(v0), h1 = f2b(v1);
        int base = (b << 10) + h;
        Ch[base] = h0;     Ch[base + 1] = h1;
        Cl[base] = f2b(v0 - b2f(h0));
        Cl[base + 1] = f2b(v1 - b2f(h1));
    }
}

extern "C" void kernel_launch(void* const* d_in, const int* in_sizes, int n_in,
                              void* d_out, int out_size, void* d_ws, size_t ws_size,
                              hipStream_t stream)
{
    const void* inputs = d_in[0];
    const void* enc    = d_in[1];
    const void* enc_c  = d_in[2];
    const void* mask   = d_in[3];
    const void* Wq   = d_in[4];
    const void* bq   = d_in[5];
    const void* Wk   = d_in[6];
    const void* bk   = d_in[7];
    const void* Wv   = d_in[8];
    const void* bv   = d_in[9];
    const void* Wo   = d_in[10];
    const void* bo   = d_in[11];
    const void* Wih0 = d_in[12];
    const void* Whh0 = d_in[13];
    const void* bih0 = d_in[14];
    const void* bhh0 = d_in[15];
    const void* Wih1 = d_in[16];
    const void* Whh1 = d_in[17];
    const void* bih1 = d_in[18];
    const void* bhh1 = d_in[19];
    float* out = (float*)d_out;
    (void)in_sizes; (void)n_in; (void)out_size; (void)ws_size;

    char* ws = (char*)d_ws;
    size_t off = 0;
    auto alloc = [&](size_t bytes) -> void* {
        void* p = ws + off; off += (bytes + 255) & ~(size_t)255; return p;
    };
    // POOL_A (37.75MB): Eh/El (split enc, dead after enc GEMMs)  ||  F0c,F0h,F1i,F1h,F0x (wfrag, loop)
    char* poolA = (char*)alloc((size_t)37748736);
    u16* Eh  = (u16*)poolA;                              // 16.8MB
    u16* El  = (u16*)(poolA + 16777216);
    u16* F0c = (u16*)poolA;                              // 8.4MB each
    u16* F0h = (u16*)(poolA + 8388608);
    u16* F1i = (u16*)(poolA + 16777216);
    u16* F1h = (u16*)(poolA + 25165824);
    u16* F0x = (u16*)(poolA + 33554432);                 // 4.2MB
    // POOL_B (16.8MB): ww-GEMM operand splits (dead after ww GEMMs)
    char* poolB = (char*)alloc((size_t)16777216);
    u16* Akh  = (u16*)poolB;
    u16* Akl  = (u16*)(poolB + 2097152);
    u16* Bqh  = (u16*)(poolB + 4194304);
    u16* Bql  = (u16*)(poolB + 6291456);
    u16* Avh  = (u16*)(poolB + 8388608);
    u16* Avl  = (u16*)(poolB + 10485760);
    u16* Both = (u16*)(poolB + 12582912);
    u16* Botl = (u16*)(poolB + 14680064);
    u16*  KQb  = (u16*)alloc((size_t)kB * kS * kH * 2);    // [b][s][n] (scale 1/32 folded)
    u16*  KQbT = (u16*)alloc((size_t)kB * kH * kS * 2);    // [b][n][s] transposed
    u16*  Vob  = (u16*)alloc((size_t)kB * kS * kH * 2);    // [b][s][o2] (incl. bvo)
    u16*  Xh   = (u16*)alloc((size_t)kB * kT * kE * 2);    // [t*32+b][e]
    u16*  Xl   = (u16*)alloc((size_t)kB * kT * kE * 2);
    u16*  Wkqh = (u16*)alloc((size_t)kH * kH * 2);
    u16*  Wkql = (u16*)alloc((size_t)kH * kH * 2);
    u16*  Wvoh = (u16*)alloc((size_t)kH * kH * 2);
    u16*  Wvol = (u16*)alloc((size_t)kH * kH * 2);
    float* pp  = (float*)alloc((size_t)4 * kB * kG * 4);   // [4][32][4096] partials (shared L0/L1)
    u16*  Ch   = (u16*)alloc((size_t)kB * kH * 2);
    u16*  Cl   = (u16*)alloc((size_t)kB * kH * 2);
    u16*  H0h  = (u16*)alloc((size_t)kB * kH * 2);
    u16*  H0l  = (u16*)alloc((size_t)kB * kH * 2);
    u16*  H1h  = (u16*)alloc((size_t)kB * kH * 2);
    u16*  H1l  = (u16*)alloc((size_t)kB * kH * 2);
    float* c0f = (float*)alloc(kB * kH * 4);
    float* c1f = (float*)alloc(kB * kH * 4);
    float* bkq = (float*)alloc(1024 * 4);
    float* bvo = (float*)alloc(1024 * 4);
    float* ubq = (float*)alloc(1024 * 4);
    float* bof = (float*)alloc(1024 * 4);
    float* bias01 = (float*)alloc(4096 * 4);
    float* bias1  = (float*)alloc(4096 * 4);
    float* cbqbk  = (float*)alloc(256);
    float* skbqs  = (float*)alloc(kB * kS * 4);
    float* maskflag = (float*)alloc(kB * kS * 4);
    int*   dtflag = (int*)alloc(256);

    // ---- one-time precompute ----
    detect_dtype_k<<<1, 256, 0, stream>>>(inputs, dtflag);
    prep_mask_k<<<1, 256, 0, stream>>>(mask, maskflag);
    prep_bias_k<<<49, 256, 0, stream>>>(Wq, bq, Wk, bk, bv, Wo, bo,
                                        bih0, bhh0, bih1, bhh1,
                                        bkq, bvo, ubq, bof, bias01, bias1, cbqbk, dtflag);
    init_state_k<<<128, 256, 0, stream>>>(enc_c, c0f, c1f, H0h, H0l, H1h, H1l, dtflag);
    split_plain_k<<<32768, 256, 0, stream>>>(enc, Eh, El, 8388608, dtflag);
    split_plain_k<<<4096, 256, 0, stream>>>(Wq, Bqh, Bql, 1048576, dtflag);
    tsplit_k<<<dim3(16, 16), 256, 0, stream>>>(Wk, 1024, 0, Akh, Akl, 1024, dtflag);
    tsplit_k<<<dim3(16, 16), 256, 0, stream>>>(Wv, 1024, 0, Avh, Avl, 1024, dtflag);
    tsplit_k<<<dim3(16, 16), 256, 0, stream>>>(Wo, 1024, 0, Both, Botl, 1024, dtflag);
    split_x_k<<<8192, 256, 0, stream>>>(inputs, Xh, Xl, dtflag);
    gemm_hilo_k<0><<<dim3(16, 16), 256, 0, stream>>>(Akh, Akl, 1024, Bqh, Bql, 1024,
                                                     Wkqh, Wkql, 1024, nullptr, 1.f);
    gemm_hilo_k<0><<<dim3(16, 16), 256, 0, stream>>>(Avh, Avl, 1024, Both, Botl, 1024,
                                                     Wvoh, Wvol, 1024, nullptr, 1.f);
    gemm_hilo_k<1><<<dim3(128, 16), 256, 0, stream>>>(Eh, El, 1024, Wkqh, Wkql, 1024,
                                                      KQb, nullptr, 0, bkq, 0.03125f);
    gemm_hilo_k<1><<<dim3(128, 16), 256, 0, stream>>>(Eh, El, 1024, Wvoh, Wvol, 1024,
                                                      Vob, nullptr, 0, bvo, 1.0f);
    kqbT_k<<<2048, 256, 0, stream>>>(KQb, KQbT);
    skbq_k<<<2048, 256, 0, stream>>>(enc, ubq, cbqbk, skbqs, dtflag);
    wfrag_k<<<256, 256, 0, stream>>>(Wih0, 1536, 0,    F0c, 32, dtflag);
    wfrag_k<<<256, 256, 0, stream>>>(Whh0, 1024, 0,    F0h, 32, dtflag);
    wfrag_k<<<256, 256, 0, stream>>>(Wih0, 1536, 1024, F0x, 16, dtflag);
    wfrag_k<<<256, 256, 0, stream>>>(Wih1, 1024, 0,    F1i, 32, dtflag);
    wfrag_k<<<256, 256, 0, stream>>>(Whh1, 1024, 0,    F1h, 32, dtflag);

    // ---- recurrent loop: 4 kernels/step ----
    for (int t = 0; t < kT; t++){
        fused_attn_k<<<32, 1024, 0, stream>>>(pp, bias1, c1f, H1h, H1l, out, t,
                                              KQbT, Vob, skbqs, maskflag, bof, Ch, Cl);
        gmm_k<0><<<dim3(64, 4), 256, 0, stream>>>(
            F0c, F0h, F0x, Ch, Cl, H0h, H0l,
            Xh + (size_t)t * 32 * kE, Xl + (size_t)t * 32 * kE, pp);
        cell0_k<<<128, 256, 0, stream>>>(pp, bias01, c0f, H0h, H0l);
        gmm_k<1><<<dim3(64, 4), 256, 0, stream>>>(
            F1i, F1h, nullptr, H0h, H0l, H1h, H1l, nullptr, nullptr, pp);
    }
    // epilogue: finish cell1 for t=127 (writes y[127]), skip attention
    fused_attn_k<<<32, 1024, 0, stream>>>(pp, bias1, c1f, H1h, H1l, out, 128,
                                          KQbT, Vob, skbqs, maskflag, bof, Ch, Cl);
}